// Round 3
// baseline (352.874 us; speedup 1.0000x reference)
//
#include <hip/hip_runtime.h>
#include <hip/hip_bf16.h>

// Attn: energies = out_state @ (history @ W.T).T ; softmax rows.
// (bias dropped: constant per softmax row -> cancels.)
// S2=S1=4096, N=1024. fp32 in/out. bf16 hi/lo 3-term GEMM folded into K=3072.
// R11: counted vmcnt w/o phase split: null (T4 needs T3). 157 us stage-2.
// R12: m201-style 2-phase x 2-barrier lockstep: stage-2 125 us, MfmaUtil 33%,
//      but 54% all-pipes-idle; stage-1 (~120 us hidden) same slot cost at
//      1/4 the FLOPs -> per-tile barrier overhead dominates both.
// R13: ONE barrier per 32k-tile, waves free-run inside the tile. All of
//      tile t is published by the boundary barrier; stage-DMAs write buf
//      (t+3)&3 whose last reader (tile t-1) drained before the previous
//      barrier (explicit lgkmcnt(0) at boundary). Reads issued in 2 cluster
//      order so compiler's counted lgkmcnt starts MFMA cluster 0 while
//      cluster 1's reads land; cross-wave, one wave's reads overlap another
//      wave's MFMAs (no lockstep). Depth-3 counted vmcnt kept (never 0
//      mid-loop). sched_barrier(0) once per tile before the boundary wait.

typedef __bf16 bf16x8 __attribute__((ext_vector_type(8)));
typedef float f32x4 __attribute__((ext_vector_type(4)));
typedef unsigned short u16x4 __attribute__((ext_vector_type(4)));

__device__ __forceinline__ unsigned short f2bf(float x) {
  unsigned int u = __float_as_uint(x);
  u += 0x7fffu + ((u >> 16) & 1u);   // RNE
  return (unsigned short)(u >> 16);
}
__device__ __forceinline__ float bf2f(unsigned short h) {
  return __uint_as_float(((unsigned int)h) << 16);
}

__device__ __forceinline__ void async_copy_16(void* lds, const void* gsrc) {
  __builtin_amdgcn_global_load_lds(
      (const __attribute__((address_space(1))) void*)gsrc,
      (__attribute__((address_space(3))) void*)lds, 16, 0, 0);
}

// compiler-fence + hw barrier: pins memory-op ordering across raw s_barrier.
__device__ __forceinline__ void barrier_fenced() {
  asm volatile("" ::: "memory");
  __builtin_amdgcn_s_barrier();
  asm volatile("" ::: "memory");
}

// Split fp32 X[rows x 1024] -> Y[rows x 3072] bf16.
// bside=0 (A-operand): [hi | lo | hi]   bside=1 (B-operand): [hi | hi | lo]
__global__ __launch_bounds__(256)
void split_kernel(const float* __restrict__ X, unsigned short* __restrict__ Y, int bside) {
  const size_t row = blockIdx.x;
  const int c4 = threadIdx.x;                       // 256 threads x 4 cols = 1024
  float4 x = ((const float4*)(X + row * 1024))[c4];
  float xs[4] = {x.x, x.y, x.z, x.w};
  u16x4 h, l;
#pragma unroll
  for (int i = 0; i < 4; ++i) {
    unsigned short hh = f2bf(xs[i]);
    h[i] = hh;
    l[i] = f2bf(xs[i] - bf2f(hh));
  }
  u16x4* y0 = (u16x4*)(Y + row * 3072 + (size_t)c4 * 4);
  if (bside) { y0[0] = h; y0[256] = h; y0[512] = l; }
  else       { y0[0] = h; y0[256] = l; y0[512] = h; }
}

// C[M,N] = A[M,K] . B[N,K]^T, bf16 in, fp32 acc. WM*WN waves (wave tile
// (BM/WM) x (BN/WN)). Fragment-ordered LDS per 32-k tile: 16-row group g at
// byte g*1024 + lane*16 (lane = kseg*16 + row) -> matches global_load_lds
// wave-uniform-base + lane*16; 2-way bank aliasing only (free) on
// ds_read_b128 frag loads. 4 buffers, depth-3 prefetch, counted vmcnt.
// Per tile (ONE barrier): issue DMAs for t+3 -> 12 ds_reads (cluster order)
// -> 2 MFMA clusters under compiler-counted lgkm -> sched_barrier ->
// s_waitcnt vmcnt(2*DM) lgkmcnt(0) -> s_barrier (publishes tile t+1).
// EPI=0: store fp32 C. EPI=1: write [hi|hi|lo] split of acc into P2.
template <int BM, int BN, int WM, int WN, int EPI, int GM, int RM, int RN, int KC>
__global__ __launch_bounds__(WM * WN * 64, 2)
void gemm_bt(const unsigned short* __restrict__ A,
             const unsigned short* __restrict__ B,
             float* __restrict__ C,
             unsigned short* __restrict__ P2,
             int M, int N) {
  constexpr int NWAVE = WM * WN;
  constexpr int MT = BM / (WM * 16);     // m-frags per wave
  constexpr int NT = BN / (WN * 16);     // n-frags per wave
  constexpr int M0 = MT / 2;             // MFMA cluster split point
  constexpr int NA = (BM / 16) / NWAVE;  // A DMA chunks per wave per tile
  constexpr int NB = (BN / 16) / NWAVE;  // B DMA chunks per wave per tile
  constexpr int DM = NA + NB;
  constexpr int NTILES = KC / 32;
  __shared__ unsigned short As[4][BM * 32];
  __shared__ unsigned short Bs[4][BN * 32];

  const int tid = threadIdx.x;
  const int w = tid >> 6;
  const int lane = tid & 63;
  const int wm = w / WN, wn = w % WN;
  const int lr = lane & 15;              // row index within 16-group
  const int ls = lane >> 4;              // k-segment (8 bf16 each)

  // XCD-aware super-tile swizzle (grid = 256 = 8 XCDs x 32, bijective)
  const int id = blockIdx.x;
  const int xcd = id & 7;
  const int j = id >> 3;
  const int bm = ((xcd % (GM / RM)) * RM + (j % RM)) * BM;
  const int bn = ((xcd / (GM / RM)) * RN + (j / RM)) * BN;

  const unsigned short* pa[NA];
#pragma unroll
  for (int c = 0; c < NA; ++c)
    pa[c] = A + (size_t)(bm + (w * NA + c) * 16 + lr) * KC + ls * 8;
  const unsigned short* pb[NB];
#pragma unroll
  for (int c = 0; c < NB; ++c)
    pb[c] = B + (size_t)(bn + (w * NB + c) * 16 + lr) * KC + ls * 8;

  f32x4 acc[MT][NT] = {};

  auto stageA = [&](int buf, int t) {
#pragma unroll
    for (int c = 0; c < NA; ++c)
      async_copy_16(&As[buf][(w * NA + c) * 512], pa[c] + t * 32);
  };
  auto stageB = [&](int buf, int t) {
#pragma unroll
    for (int c = 0; c < NB; ++c)
      async_copy_16(&Bs[buf][(w * NB + c) * 512], pb[c] + t * 32);
  };

  // prologue: stage tiles 0..2 (depth-3), wait tile 0, publish
  stageA(0, 0); stageB(0, 0);
  stageA(1, 1); stageB(1, 1);
  stageA(2, 2); stageB(2, 2);
  asm volatile("s_waitcnt vmcnt(%0)" :: "n"(2 * DM) : "memory");
  barrier_fenced();

#pragma unroll 1
  for (int t = 0; t < NTILES; ++t) {
    const int buf = t & 3;
    const int nbuf = (t + 3) & 3;

    // issue next prefetch first (earliest in flight; writes buf (t+3)&3,
    // whose last reader -- tile t-1 -- drained before the last barrier)
    if (t < NTILES - 3) { stageA(nbuf, t + 3); stageB(nbuf, t + 3); }

    // fragment reads in cluster order: [A 0..M0) + B all] then [A M0..MT).
    // Compiler emits counted lgkmcnt: cluster-0 MFMAs start while the
    // trailing A-reads are still landing.
    bf16x8 af[MT], bfr[NT];
#pragma unroll
    for (int mt = 0; mt < M0; ++mt)
      af[mt] = *(const bf16x8*)&As[buf][(wm * MT + mt) * 512 + ls * 128 + lr * 8];
#pragma unroll
    for (int nt = 0; nt < NT; ++nt)
      bfr[nt] = *(const bf16x8*)&Bs[buf][(wn * NT + nt) * 512 + ls * 128 + lr * 8];
#pragma unroll
    for (int mt = M0; mt < MT; ++mt)
      af[mt] = *(const bf16x8*)&As[buf][(wm * MT + mt) * 512 + ls * 128 + lr * 8];

    __builtin_amdgcn_s_setprio(1);
#pragma unroll
    for (int mt = 0; mt < MT; ++mt)
#pragma unroll
      for (int nt = 0; nt < NT; ++nt)
        acc[mt][nt] = __builtin_amdgcn_mfma_f32_16x16x32_bf16(af[mt], bfr[nt], acc[mt][nt], 0, 0, 0);
    __builtin_amdgcn_s_setprio(0);

    // boundary: publish tile t+1 (its DMAs were issued 3 slots ago); keep
    // t+2/t+3 in flight. lgkmcnt(0): our ds_reads of buf t are drained
    // before anyone may overwrite it (as nbuf of iter t+1).
    __builtin_amdgcn_sched_barrier(0);
    if (t < NTILES - 3)
      asm volatile("s_waitcnt vmcnt(%0) lgkmcnt(0)" :: "n"(2 * DM) : "memory");
    else if (t == NTILES - 3)
      asm volatile("s_waitcnt vmcnt(%0) lgkmcnt(0)" :: "n"(DM) : "memory");
    else
      asm volatile("s_waitcnt vmcnt(0) lgkmcnt(0)" ::: "memory");
    barrier_fenced();
  }

  // Epilogue. C/D layout (m89/m91): col(n) = lane&15, row(m) = (lane>>4)*4 + reg.
  const int cm0 = bm + wm * (BM / WM);
  const int cn0 = bn + wn * (BN / WN);
#pragma unroll
  for (int mt = 0; mt < MT; ++mt) {
#pragma unroll
    for (int nt = 0; nt < NT; ++nt) {
      const int col = cn0 + nt * 16 + lr;
      const int row0 = cm0 + mt * 16 + ls * 4;
      if constexpr (EPI == 0) {
#pragma unroll
        for (int r = 0; r < 4; ++r)
          C[(size_t)(row0 + r) * N + col] = acc[mt][nt][r];
      } else {
#pragma unroll
        for (int r = 0; r < 4; ++r) {
          const float p = acc[mt][nt][r];
          const unsigned short h = f2bf(p);
          const unsigned short l = f2bf(p - bf2f(h));
          const size_t base = (size_t)(row0 + r) * 3072 + col;
          P2[base] = h;
          P2[base + 1024] = h;
          P2[base + 2048] = l;
        }
      }
    }
  }
}

// In-place row softmax, N=4096, one block per row, 16 floats/thread in regs.
__global__ __launch_bounds__(256)
void softmax_inplace(float* __restrict__ C, int N) {
  float4* r4 = (float4*)(C + (size_t)blockIdx.x * N);
  const int t = threadIdx.x;
  float4 v[4];
  float mx = -3.0e38f;
#pragma unroll
  for (int i = 0; i < 4; ++i) {
    v[i] = r4[t + i * 256];
    mx = fmaxf(mx, fmaxf(fmaxf(v[i].x, v[i].y), fmaxf(v[i].z, v[i].w)));
  }
#pragma unroll
  for (int o = 32; o; o >>= 1) mx = fmaxf(mx, __shfl_xor(mx, o, 64));
  __shared__ float smax[4], ssum[4];
  const int w = t >> 6;
  if ((t & 63) == 0) smax[w] = mx;
  __syncthreads();
  mx = fmaxf(fmaxf(smax[0], smax[1]), fmaxf(smax[2], smax[3]));
  float s = 0.f;
#pragma unroll
  for (int i = 0; i < 4; ++i) {
    v[i].x = __expf(v[i].x - mx);
    v[i].y = __expf(v[i].y - mx);
    v[i].z = __expf(v[i].z - mx);
    v[i].w = __expf(v[i].w - mx);
    s += (v[i].x + v[i].y) + (v[i].z + v[i].w);
  }
#pragma unroll
  for (int o = 32; o; o >>= 1) s += __shfl_xor(s, o, 64);
  if ((t & 63) == 0) ssum[w] = s;
  __syncthreads();
  const float inv = 1.0f / (ssum[0] + ssum[1] + ssum[2] + ssum[3]);
#pragma unroll
  for (int i = 0; i < 4; ++i) {
    v[i].x *= inv; v[i].y *= inv; v[i].z *= inv; v[i].w *= inv;
    r4[t + i * 256] = v[i];
  }
}

extern "C" void kernel_launch(void* const* d_in, const int* in_sizes, int n_in,
                              void* d_out, int out_size, void* d_ws, size_t ws_size,
                              hipStream_t stream) {
  const float* out_state = (const float*)d_in[0];  // [4096,1024]
  const float* history   = (const float*)d_in[1];  // [4096,1024]
  const float* W         = (const float*)d_in[2];  // [1024,1024]
  float* out = (float*)d_out;                      // [4096,4096]

  unsigned short* H2 = (unsigned short*)d_ws;                 // 4096x3072
  unsigned short* W2 = H2 + (size_t)4096 * 3072;              // 1024x3072
  unsigned short* A2 = W2 + (size_t)1024 * 3072;              // 4096x3072
  unsigned short* P2 = A2 + (size_t)4096 * 3072;              // 4096x3072

  split_kernel<<<4096, 256, 0, stream>>>(history, H2, 0);
  split_kernel<<<1024, 256, 0, stream>>>(W, W2, 1);
  split_kernel<<<4096, 256, 0, stream>>>(out_state, A2, 0);

  // proj -> P2 split. 128x128 tile, 8 waves (wave tile 64x32), 1-barrier
  // tiles, 4-buf depth-3, vmcnt(4). Grid 32x8 = 256 blocks.
  gemm_bt<128, 128, 2, 4, 1, 32, 8, 4, 3072><<<256, 512, 0, stream>>>(
      H2, W2, nullptr, P2, 4096, 1024);

  // energies -> d_out. 256x256 tile, 8 waves (wave tile 128x64), 1-barrier
  // tiles, 4-buf depth-3, vmcnt(8). 16x16 = 256 blocks.
  gemm_bt<256, 256, 2, 4, 0, 16, 4, 8, 3072><<<256, 512, 0, stream>>>(
      A2, P2, out, nullptr, 4096, 4096);

  softmax_inplace<<<4096, 256, 0, stream>>>(out, 4096);
}

// Round 4
// 283.244 us; speedup vs baseline: 1.2458x; 1.2458x over previous
//
#include <hip/hip_runtime.h>
#include <hip/hip_bf16.h>

// Attn: energies = out_state @ (history @ W.T).T ; softmax rows.
// (bias dropped: constant per softmax row -> cancels.)
// S2=S1=4096, N=1024. fp32 in/out. bf16 hi/lo 3-term GEMM folded into K=3072.
// R11: counted vmcnt w/o phase split: null (T4 needs T3). 157 us stage-2.
// R12: 2-phase lockstep {reads -> bar -> lgkm0 -> 16 MFMA -> bar} + 4-buf
//      depth-3 counted vmcnt: stage-2 125 us @ MfmaUtil 33. BEST schedule.
// R13: 1-barrier free-run: 167 us. REGRESSION -> fine interleave is the
//      lever (m196 confirmed on our HW); lockstep rhythm restored.
// R14: stage-1 was the hidden elephant (~120 us for 1/4 the FLOPs): its
//      phases carried only 4 MFMA per barrier-slot. Fix: BK=64 (KU=2
//      sub-slabs) + PH=1 -> 16 MFMA + 12 reads + 2 barriers per tile,
//      48 tiles (slot count 384 -> 96). LDS 128 KB is free (grid 256 =
//      1 block/CU either way). Stage-2 kept R12-exact.

typedef __bf16 bf16x8 __attribute__((ext_vector_type(8)));
typedef float f32x4 __attribute__((ext_vector_type(4)));
typedef unsigned short u16x4 __attribute__((ext_vector_type(4)));

__device__ __forceinline__ unsigned short f2bf(float x) {
  unsigned int u = __float_as_uint(x);
  u += 0x7fffu + ((u >> 16) & 1u);   // RNE
  return (unsigned short)(u >> 16);
}
__device__ __forceinline__ float bf2f(unsigned short h) {
  return __uint_as_float(((unsigned int)h) << 16);
}

__device__ __forceinline__ void async_copy_16(void* lds, const void* gsrc) {
  __builtin_amdgcn_global_load_lds(
      (const __attribute__((address_space(1))) void*)gsrc,
      (__attribute__((address_space(3))) void*)lds, 16, 0, 0);
}

// compiler-fence + hw barrier: pins memory-op ordering across raw s_barrier.
__device__ __forceinline__ void barrier_fenced() {
  asm volatile("" ::: "memory");
  __builtin_amdgcn_s_barrier();
  asm volatile("" ::: "memory");
}

// Split fp32 X[rows x 1024] -> Y[rows x 3072] bf16.
// bside=0 (A-operand): [hi | lo | hi]   bside=1 (B-operand): [hi | hi | lo]
__global__ __launch_bounds__(256)
void split_kernel(const float* __restrict__ X, unsigned short* __restrict__ Y, int bside) {
  const size_t row = blockIdx.x;
  const int c4 = threadIdx.x;                       // 256 threads x 4 cols = 1024
  float4 x = ((const float4*)(X + row * 1024))[c4];
  float xs[4] = {x.x, x.y, x.z, x.w};
  u16x4 h, l;
#pragma unroll
  for (int i = 0; i < 4; ++i) {
    unsigned short hh = f2bf(xs[i]);
    h[i] = hh;
    l[i] = f2bf(xs[i] - bf2f(hh));
  }
  u16x4* y0 = (u16x4*)(Y + row * 3072 + (size_t)c4 * 4);
  if (bside) { y0[0] = h; y0[256] = h; y0[512] = l; }
  else       { y0[0] = h; y0[256] = l; y0[512] = h; }
}

// C[M,N] = A[M,K] . B[N,K]^T, bf16 in, fp32 acc. WM*WN waves (wave tile
// (BM/WM) x (BN/WN)). Fragment-ordered LDS per 32-k sub-slab: 16-row group g
// at byte g*1024 + lane*16 (lane = kseg*16 + row) -> matches global_load_lds
// wave-uniform-base + lane*16; 2-way bank aliasing only (free) on
// ds_read_b128 frag loads. 4 buffers of BK=32*KU, depth-3 prefetch, counted
// vmcnt. Per tile: PH lockstep phases, each {frag reads + DMA issue -> bar
// -> lgkmcnt(0) -> setprio(1) MFMA setprio(0)}; boundary: sched_barrier ->
// vmcnt(2*DM | DM | 0) -> bar (publishes tile t+1, keeps t+2/t+3 in flight).
// EPI=0: store fp32 C. EPI=1: write [hi|hi|lo] split of acc into P2.
template <int BM, int BN, int WM, int WN, int KU, int PH, int EPI,
          int GM, int RM, int RN, int KC>
__global__ __launch_bounds__(WM * WN * 64, 2)
void gemm_bt(const unsigned short* __restrict__ A,
             const unsigned short* __restrict__ B,
             float* __restrict__ C,
             unsigned short* __restrict__ P2,
             int M, int N) {
  constexpr int NWAVE = WM * WN;
  constexpr int MT = BM / (WM * 16);     // m-frags per wave
  constexpr int NT = BN / (WN * 16);     // n-frags per wave
  constexpr int M0 = (PH == 2) ? MT / 2 : MT;
  constexpr int NA = (BM / 16) / NWAVE;  // A DMA chunks per wave per sub-slab
  constexpr int NB = (BN / 16) / NWAVE;  // B DMA chunks per wave per sub-slab
  constexpr int DM = KU * (NA + NB);     // DMA instrs per tile per wave
  constexpr int NTILES = KC / (32 * KU);
  __shared__ unsigned short As[4][KU * BM * 32];
  __shared__ unsigned short Bs[4][KU * BN * 32];

  const int tid = threadIdx.x;
  const int w = tid >> 6;
  const int lane = tid & 63;
  const int wm = w / WN, wn = w % WN;
  const int lr = lane & 15;              // row index within 16-group
  const int ls = lane >> 4;              // k-segment (8 bf16 each)

  // XCD-aware super-tile swizzle (grid = 256 = 8 XCDs x 32, bijective)
  const int id = blockIdx.x;
  const int xcd = id & 7;
  const int j = id >> 3;
  const int bm = ((xcd % (GM / RM)) * RM + (j % RM)) * BM;
  const int bn = ((xcd / (GM / RM)) * RN + (j / RM)) * BN;

  const unsigned short* pa[NA];
#pragma unroll
  for (int c = 0; c < NA; ++c)
    pa[c] = A + (size_t)(bm + (w * NA + c) * 16 + lr) * KC + ls * 8;
  const unsigned short* pb[NB];
#pragma unroll
  for (int c = 0; c < NB; ++c)
    pb[c] = B + (size_t)(bn + (w * NB + c) * 16 + lr) * KC + ls * 8;

  f32x4 acc[MT][NT] = {};

  auto stageA = [&](int buf, int t) {
#pragma unroll
    for (int u = 0; u < KU; ++u)
#pragma unroll
      for (int c = 0; c < NA; ++c)
        async_copy_16(&As[buf][u * BM * 32 + (w * NA + c) * 512],
                      pa[c] + t * 32 * KU + u * 32);
  };
  auto stageB = [&](int buf, int t) {
#pragma unroll
    for (int u = 0; u < KU; ++u)
#pragma unroll
      for (int c = 0; c < NB; ++c)
        async_copy_16(&Bs[buf][u * BN * 32 + (w * NB + c) * 512],
                      pb[c] + t * 32 * KU + u * 32);
  };

  // prologue: stage tiles 0..2 (depth-3), wait tile 0, publish
  stageA(0, 0); stageB(0, 0);
  stageA(1, 1); stageB(1, 1);
  stageA(2, 2); stageB(2, 2);
  asm volatile("s_waitcnt vmcnt(%0)" :: "n"(2 * DM) : "memory");
  barrier_fenced();

#pragma unroll 1
  for (int t = 0; t < NTILES; ++t) {
    const int buf = t & 3;
    const int nbuf = (t + 3) & 3;
    const bool st = (t < NTILES - 3);

    // ---- phase 0: A-frags [0,M0) + all B-frags; issue A DMAs for t+3 ----
    bf16x8 af[KU][M0], bfr[KU][NT];
#pragma unroll
    for (int u = 0; u < KU; ++u) {
#pragma unroll
      for (int mt = 0; mt < M0; ++mt)
        af[u][mt] = *(const bf16x8*)&As[buf][u * BM * 32 + (wm * MT + mt) * 512 + ls * 128 + lr * 8];
#pragma unroll
      for (int nt = 0; nt < NT; ++nt)
        bfr[u][nt] = *(const bf16x8*)&Bs[buf][u * BN * 32 + (wn * NT + nt) * 512 + ls * 128 + lr * 8];
    }
    if (st) stageA(nbuf, t + 3);
    if constexpr (PH == 1) { if (st) stageB(nbuf, t + 3); }
    barrier_fenced();
    asm volatile("s_waitcnt lgkmcnt(0)" ::: "memory");
    __builtin_amdgcn_sched_barrier(0);
    __builtin_amdgcn_s_setprio(1);
#pragma unroll
    for (int u = 0; u < KU; ++u)
#pragma unroll
      for (int mt = 0; mt < M0; ++mt)
#pragma unroll
        for (int nt = 0; nt < NT; ++nt)
          acc[mt][nt] = __builtin_amdgcn_mfma_f32_16x16x32_bf16(af[u][mt], bfr[u][nt], acc[mt][nt], 0, 0, 0);
    __builtin_amdgcn_s_setprio(0);
    __builtin_amdgcn_sched_barrier(0);

    // ---- phase 1 (PH==2): A-frags [M0,MT), reuse B regs; issue B DMAs ----
    if constexpr (PH == 2) {
      barrier_fenced();
      bf16x8 ag[KU][MT - M0];
#pragma unroll
      for (int u = 0; u < KU; ++u)
#pragma unroll
        for (int mt = 0; mt < MT - M0; ++mt)
          ag[u][mt] = *(const bf16x8*)&As[buf][u * BM * 32 + (wm * MT + M0 + mt) * 512 + ls * 128 + lr * 8];
      if (st) stageB(nbuf, t + 3);
      barrier_fenced();
      asm volatile("s_waitcnt lgkmcnt(0)" ::: "memory");
      __builtin_amdgcn_sched_barrier(0);
      __builtin_amdgcn_s_setprio(1);
#pragma unroll
      for (int u = 0; u < KU; ++u)
#pragma unroll
        for (int mt = 0; mt < MT - M0; ++mt)
#pragma unroll
          for (int nt = 0; nt < NT; ++nt)
            acc[M0 + mt][nt] = __builtin_amdgcn_mfma_f32_16x16x32_bf16(ag[u][mt], bfr[u][nt], acc[M0 + mt][nt], 0, 0, 0);
      __builtin_amdgcn_s_setprio(0);
      __builtin_amdgcn_sched_barrier(0);
    }

    // ---- boundary: tile t+1 must be landed; keep t+2/t+3 in flight ----
    if (t < NTILES - 3)
      asm volatile("s_waitcnt vmcnt(%0)" :: "n"(2 * DM) : "memory");
    else if (t == NTILES - 3)
      asm volatile("s_waitcnt vmcnt(%0)" :: "n"(DM) : "memory");
    else
      asm volatile("s_waitcnt vmcnt(0)" ::: "memory");
    barrier_fenced();
  }

  // Epilogue. C/D layout (m89/m91): col(n) = lane&15, row(m) = (lane>>4)*4 + reg.
  const int cm0 = bm + wm * (BM / WM);
  const int cn0 = bn + wn * (BN / WN);
#pragma unroll
  for (int mt = 0; mt < MT; ++mt) {
#pragma unroll
    for (int nt = 0; nt < NT; ++nt) {
      const int col = cn0 + nt * 16 + lr;
      const int row0 = cm0 + mt * 16 + ls * 4;
      if constexpr (EPI == 0) {
#pragma unroll
        for (int r = 0; r < 4; ++r)
          C[(size_t)(row0 + r) * N + col] = acc[mt][nt][r];
      } else {
#pragma unroll
        for (int r = 0; r < 4; ++r) {
          const float p = acc[mt][nt][r];
          const unsigned short h = f2bf(p);
          const unsigned short l = f2bf(p - bf2f(h));
          const size_t base = (size_t)(row0 + r) * 3072 + col;
          P2[base] = h;
          P2[base + 1024] = h;
          P2[base + 2048] = l;
        }
      }
    }
  }
}

// In-place row softmax, N=4096, one block per row, 16 floats/thread in regs.
__global__ __launch_bounds__(256)
void softmax_inplace(float* __restrict__ C, int N) {
  float4* r4 = (float4*)(C + (size_t)blockIdx.x * N);
  const int t = threadIdx.x;
  float4 v[4];
  float mx = -3.0e38f;
#pragma unroll
  for (int i = 0; i < 4; ++i) {
    v[i] = r4[t + i * 256];
    mx = fmaxf(mx, fmaxf(fmaxf(v[i].x, v[i].y), fmaxf(v[i].z, v[i].w)));
  }
#pragma unroll
  for (int o = 32; o; o >>= 1) mx = fmaxf(mx, __shfl_xor(mx, o, 64));
  __shared__ float smax[4], ssum[4];
  const int w = t >> 6;
  if ((t & 63) == 0) smax[w] = mx;
  __syncthreads();
  mx = fmaxf(fmaxf(smax[0], smax[1]), fmaxf(smax[2], smax[3]));
  float s = 0.f;
#pragma unroll
  for (int i = 0; i < 4; ++i) {
    v[i].x = __expf(v[i].x - mx);
    v[i].y = __expf(v[i].y - mx);
    v[i].z = __expf(v[i].z - mx);
    v[i].w = __expf(v[i].w - mx);
    s += (v[i].x + v[i].y) + (v[i].z + v[i].w);
  }
#pragma unroll
  for (int o = 32; o; o >>= 1) s += __shfl_xor(s, o, 64);
  if ((t & 63) == 0) ssum[w] = s;
  __syncthreads();
  const float inv = 1.0f / (ssum[0] + ssum[1] + ssum[2] + ssum[3]);
#pragma unroll
  for (int i = 0; i < 4; ++i) {
    v[i].x *= inv; v[i].y *= inv; v[i].z *= inv; v[i].w *= inv;
    r4[t + i * 256] = v[i];
  }
}

extern "C" void kernel_launch(void* const* d_in, const int* in_sizes, int n_in,
                              void* d_out, int out_size, void* d_ws, size_t ws_size,
                              hipStream_t stream) {
  const float* out_state = (const float*)d_in[0];  // [4096,1024]
  const float* history   = (const float*)d_in[1];  // [4096,1024]
  const float* W         = (const float*)d_in[2];  // [1024,1024]
  float* out = (float*)d_out;                      // [4096,4096]

  unsigned short* H2 = (unsigned short*)d_ws;                 // 4096x3072
  unsigned short* W2 = H2 + (size_t)4096 * 3072;              // 1024x3072
  unsigned short* A2 = W2 + (size_t)1024 * 3072;              // 4096x3072
  unsigned short* P2 = A2 + (size_t)4096 * 3072;              // 4096x3072

  split_kernel<<<4096, 256, 0, stream>>>(history, H2, 0);
  split_kernel<<<1024, 256, 0, stream>>>(W, W2, 1);
  split_kernel<<<4096, 256, 0, stream>>>(out_state, A2, 0);

  // proj -> P2 split. 128x128 tile, 8 waves, BK=64 (KU=2), PH=1:
  // 16 MFMA + 12 reads + 4 DMAs per tile, 2 barriers/tile, 48 tiles.
  // LDS 128 KB (grid 256 = 1 block/CU anyway). vmcnt(8/4/0).
  gemm_bt<128, 128, 2, 4, 2, 1, 1, 32, 8, 4, 3072><<<256, 512, 0, stream>>>(
      H2, W2, nullptr, P2, 4096, 1024);

  // energies -> d_out. R12-exact: 256x256, 8 waves, KU=1, PH=2 (16 MFMA per
  // phase), 4-buf depth-3, vmcnt(8/4/0). 256 blocks.
  gemm_bt<256, 256, 2, 4, 1, 2, 0, 16, 4, 8, 3072><<<256, 512, 0, stream>>>(
      A2, P2, out, nullptr, 4096, 4096);

  softmax_inplace<<<4096, 256, 0, stream>>>(out, 4096);
}

// Round 5
// 259.053 us; speedup vs baseline: 1.3622x; 1.0934x over previous
//
#include <hip/hip_runtime.h>
#include <hip/hip_bf16.h>

// Attn: energies = out_state @ (history @ W.T).T ; softmax rows.
// (bias dropped: constant per softmax row -> cancels.)
// S2=S1=4096, N=1024. fp32 in/out. bf16 hi/lo GEMM, 3 products.
// R12: 2-phase lockstep + depth-3 counted vmcnt: stage-2 125-129 us. BEST sched.
// R13: free-run: regression. R14: stage-1 KU=2: null (~110 us).
// R15 DIAGNOSIS: stage-2 staged bytes = 768 MB / 129.5 us = 5.93 TB/s ==
//   the VM-path ceiling; staging-THROUGHPUT-bound (FETCH only 74 MB; L2/L3
//   serve reuse but every byte rides the per-CU path at ~10 B/cyc/CU).
//   Schedule surgery can't move it; staged bytes can.
// R15: hi/lo as SEPARATE arrays (Ah,Al,Bh,Bl). Same 3 products
//   (Ah.Bh + Al.Bh + Ah.Bl over K=1024) staged from 4 distinct slabs
//   instead of 6 concatenated (old [hi|lo|hi].[hi|hi|lo] staged hi twice
//   per side): -33% staged bytes, -33% ds_reads (reg-reuse across
//   products), -33% split/P-epilogue writes. Bit-identical numerics.
//   Stage-2: 256x256, 2 bufs x 64 KB, depth-1 (drain boundary is
//   rate-limited anyway). Stage-1: 128x128, 4 bufs x 32 KB, depth-3.

typedef __bf16 bf16x8 __attribute__((ext_vector_type(8)));
typedef float f32x4 __attribute__((ext_vector_type(4)));
typedef unsigned short u16x4 __attribute__((ext_vector_type(4)));

__device__ __forceinline__ unsigned short f2bf(float x) {
  unsigned int u = __float_as_uint(x);
  u += 0x7fffu + ((u >> 16) & 1u);   // RNE
  return (unsigned short)(u >> 16);
}
__device__ __forceinline__ float bf2f(unsigned short h) {
  return __uint_as_float(((unsigned int)h) << 16);
}

__device__ __forceinline__ void async_copy_16(void* lds, const void* gsrc) {
  __builtin_amdgcn_global_load_lds(
      (const __attribute__((address_space(1))) void*)gsrc,
      (__attribute__((address_space(3))) void*)lds, 16, 0, 0);
}

// compiler-fence + hw barrier: pins memory-op ordering across raw s_barrier.
__device__ __forceinline__ void barrier_fenced() {
  asm volatile("" ::: "memory");
  __builtin_amdgcn_s_barrier();
  asm volatile("" ::: "memory");
}

// Split fp32 X[rows x 1024] -> Yh, Yl [rows x 1024] bf16 (hi + residual-lo).
__global__ __launch_bounds__(256)
void split_kernel(const float* __restrict__ X, unsigned short* __restrict__ Yh,
                  unsigned short* __restrict__ Yl) {
  const size_t row = blockIdx.x;
  const int c4 = threadIdx.x;                       // 256 threads x 4 cols = 1024
  float4 x = ((const float4*)(X + row * 1024))[c4];
  float xs[4] = {x.x, x.y, x.z, x.w};
  u16x4 h, l;
#pragma unroll
  for (int i = 0; i < 4; ++i) {
    unsigned short hh = f2bf(xs[i]);
    h[i] = hh;
    l[i] = f2bf(xs[i] - bf2f(hh));
  }
  ((u16x4*)(Yh + row * 1024))[c4] = h;
  ((u16x4*)(Yl + row * 1024))[c4] = l;
}

// C[M,N] = (Ah+Al)[M,K] . (Bh+Bl)[N,K]^T first-order: Ah.Bh + Al.Bh + Ah.Bl,
// K=1024, bf16 in fp32 acc. WM*WN waves, wave tile (BM/WM)x(BN/WN).
// Fragment-ordered LDS per 32-k slab: 16-row group g at byte g*1024+lane*16
// (lane = kseg*16+row) == global_load_lds wave-uniform-base + lane*16;
// 2-way bank aliasing only (free) on ds_read_b128.
// Lockstep phases (R12 rhythm): {reads + DMA-issue -> bar -> lgkmcnt(0) ->
// setprio(1) MFMA setprio(0)}; boundary: sched_bar -> vmcnt -> bar.
// NBUF buffers, DEPTH-deep prefetch (1: drain boundary; 3: counted vmcnt).
// EPI=0: store fp32 C. EPI=1: store hi/lo split into Ph,Pl.
template <int BM, int BN, int WM, int WN, int NBUF, int DEPTH, int EPI,
          int GM, int RM, int RN>
__global__ __launch_bounds__(WM * WN * 64, 2)
void gemm4(const unsigned short* __restrict__ Ah, const unsigned short* __restrict__ Al,
           const unsigned short* __restrict__ Bh, const unsigned short* __restrict__ Bl,
           float* __restrict__ C,
           unsigned short* __restrict__ Ph, unsigned short* __restrict__ Pl,
           int M, int N) {
  constexpr int NWAVE = WM * WN;
  constexpr int MT = BM / (WM * 16);     // m-frags per wave (8 or 4)
  constexpr int NT = BN / (WN * 16);     // n-frags per wave (4 or 2)
  constexpr int NA = (BM / 16) / NWAVE;  // chunks per wave per array (A-side)
  constexpr int NB = (BN / 16) / NWAVE;  // chunks per wave per array (B-side)
  constexpr int DM = 2 * (NA + NB);      // DMA instrs per slab per wave
  constexpr int NTILES = 32;             // K = 1024, BK = 32
  __shared__ unsigned short AhS[NBUF][BM * 32];
  __shared__ unsigned short AlS[NBUF][BM * 32];
  __shared__ unsigned short BhS[NBUF][BN * 32];
  __shared__ unsigned short BlS[NBUF][BN * 32];

  const int tid = threadIdx.x;
  const int w = tid >> 6;
  const int lane = tid & 63;
  const int wm = w / WN, wn = w % WN;
  const int lr = lane & 15;              // row index within 16-group
  const int ls = lane >> 4;              // k-segment (8 bf16 each)

  // XCD-aware super-tile swizzle (grid = 256 = 8 XCDs x 32, bijective)
  const int id = blockIdx.x;
  const int xcd = id & 7;
  const int j = id >> 3;
  const int bm = ((xcd % (GM / RM)) * RM + (j % RM)) * BM;
  const int bn = ((xcd / (GM / RM)) * RN + (j / RM)) * BN;

  const unsigned short *pah[NA], *pal[NA];
#pragma unroll
  for (int c = 0; c < NA; ++c) {
    const size_t r = (size_t)(bm + (w * NA + c) * 16 + lr) * 1024 + ls * 8;
    pah[c] = Ah + r; pal[c] = Al + r;
  }
  const unsigned short *pbh[NB], *pbl[NB];
#pragma unroll
  for (int c = 0; c < NB; ++c) {
    const size_t r = (size_t)(bn + (w * NB + c) * 16 + lr) * 1024 + ls * 8;
    pbh[c] = Bh + r; pbl[c] = Bl + r;
  }

  f32x4 acc[MT][NT] = {};

  auto stageAh = [&](int buf, int t) {
#pragma unroll
    for (int c = 0; c < NA; ++c)
      async_copy_16(&AhS[buf][(w * NA + c) * 512], pah[c] + t * 32);
  };
  auto stageAl = [&](int buf, int t) {
#pragma unroll
    for (int c = 0; c < NA; ++c)
      async_copy_16(&AlS[buf][(w * NA + c) * 512], pal[c] + t * 32);
  };
  auto stageBh = [&](int buf, int t) {
#pragma unroll
    for (int c = 0; c < NB; ++c)
      async_copy_16(&BhS[buf][(w * NB + c) * 512], pbh[c] + t * 32);
  };
  auto stageBl = [&](int buf, int t) {
#pragma unroll
    for (int c = 0; c < NB; ++c)
      async_copy_16(&BlS[buf][(w * NB + c) * 512], pbl[c] + t * 32);
  };

  auto LDAh = [&](int buf, int g) { return *(const bf16x8*)&AhS[buf][g * 512 + ls * 128 + lr * 8]; };
  auto LDAl = [&](int buf, int g) { return *(const bf16x8*)&AlS[buf][g * 512 + ls * 128 + lr * 8]; };
  auto LDBh = [&](int buf, int g) { return *(const bf16x8*)&BhS[buf][g * 512 + ls * 128 + lr * 8]; };
  auto LDBl = [&](int buf, int g) { return *(const bf16x8*)&BlS[buf][g * 512 + ls * 128 + lr * 8]; };

  // prologue: stage slabs 0..DEPTH-1
#pragma unroll
  for (int d = 0; d < DEPTH; ++d) {
    stageAh(d % NBUF, d); stageAl(d % NBUF, d);
    stageBh(d % NBUF, d); stageBl(d % NBUF, d);
  }
  if constexpr (DEPTH == 1)
    asm volatile("s_waitcnt vmcnt(0)" ::: "memory");
  else
    asm volatile("s_waitcnt vmcnt(%0)" :: "n"(2 * DM) : "memory");
  barrier_fenced();

#pragma unroll 1
  for (int t = 0; t < NTILES; ++t) {
    const int buf = t % NBUF;
    const int nbuf = (t + DEPTH) % NBUF;
    const int ts = t + DEPTH;            // slab being prefetched
    const bool st = (ts < NTILES);

    if constexpr (MT == 8) {
      // ---- stage-2 shape: 5 bar-windows x 16/16/16/16/32 MFMA ----
      bf16x8 ah[8], al[8], bh[NT], bl[NT];
      // ph0: Ah[0..4) + Bh; issue Ah DMAs
#pragma unroll
      for (int mt = 0; mt < 4; ++mt) ah[mt] = LDAh(buf, wm * MT + mt);
#pragma unroll
      for (int nt = 0; nt < NT; ++nt) bh[nt] = LDBh(buf, wn * NT + nt);
      if (st) stageAh(nbuf, ts);
      barrier_fenced();
      asm volatile("s_waitcnt lgkmcnt(0)" ::: "memory");
      __builtin_amdgcn_sched_barrier(0);
      __builtin_amdgcn_s_setprio(1);
#pragma unroll
      for (int mt = 0; mt < 4; ++mt)
#pragma unroll
        for (int nt = 0; nt < NT; ++nt)
          acc[mt][nt] = __builtin_amdgcn_mfma_f32_16x16x32_bf16(ah[mt], bh[nt], acc[mt][nt], 0, 0, 0);
      __builtin_amdgcn_s_setprio(0);
      __builtin_amdgcn_sched_barrier(0);
      // ph1: Ah[4..8); issue Bh DMAs
      barrier_fenced();
#pragma unroll
      for (int mt = 4; mt < 8; ++mt) ah[mt] = LDAh(buf, wm * MT + mt);
      if (st) stageBh(nbuf, ts);
      barrier_fenced();
      asm volatile("s_waitcnt lgkmcnt(0)" ::: "memory");
      __builtin_amdgcn_sched_barrier(0);
      __builtin_amdgcn_s_setprio(1);
#pragma unroll
      for (int mt = 4; mt < 8; ++mt)
#pragma unroll
        for (int nt = 0; nt < NT; ++nt)
          acc[mt][nt] = __builtin_amdgcn_mfma_f32_16x16x32_bf16(ah[mt], bh[nt], acc[mt][nt], 0, 0, 0);
      __builtin_amdgcn_s_setprio(0);
      __builtin_amdgcn_sched_barrier(0);
      // ph2: Bl; issue Al DMAs
      barrier_fenced();
#pragma unroll
      for (int nt = 0; nt < NT; ++nt) bl[nt] = LDBl(buf, wn * NT + nt);
      if (st) stageAl(nbuf, ts);
      barrier_fenced();
      asm volatile("s_waitcnt lgkmcnt(0)" ::: "memory");
      __builtin_amdgcn_sched_barrier(0);
      __builtin_amdgcn_s_setprio(1);
#pragma unroll
      for (int mt = 0; mt < 4; ++mt)
#pragma unroll
        for (int nt = 0; nt < NT; ++nt)
          acc[mt][nt] = __builtin_amdgcn_mfma_f32_16x16x32_bf16(ah[mt], bl[nt], acc[mt][nt], 0, 0, 0);
      __builtin_amdgcn_s_setprio(0);
      __builtin_amdgcn_sched_barrier(0);
      // ph3: Al[0..4); issue Bl DMAs
      barrier_fenced();
#pragma unroll
      for (int mt = 0; mt < 4; ++mt) al[mt] = LDAl(buf, wm * MT + mt);
      if (st) stageBl(nbuf, ts);
      barrier_fenced();
      asm volatile("s_waitcnt lgkmcnt(0)" ::: "memory");
      __builtin_amdgcn_sched_barrier(0);
      __builtin_amdgcn_s_setprio(1);
#pragma unroll
      for (int mt = 4; mt < 8; ++mt)
#pragma unroll
        for (int nt = 0; nt < NT; ++nt)
          acc[mt][nt] = __builtin_amdgcn_mfma_f32_16x16x32_bf16(ah[mt], bl[nt], acc[mt][nt], 0, 0, 0);
      __builtin_amdgcn_s_setprio(0);
      __builtin_amdgcn_sched_barrier(0);
      // ph4: Al[4..8); Al x Bh (32 MFMA in one window)
      barrier_fenced();
#pragma unroll
      for (int mt = 4; mt < 8; ++mt) al[mt] = LDAl(buf, wm * MT + mt);
      barrier_fenced();
      asm volatile("s_waitcnt lgkmcnt(0)" ::: "memory");
      __builtin_amdgcn_sched_barrier(0);
      __builtin_amdgcn_s_setprio(1);
#pragma unroll
      for (int mt = 0; mt < 8; ++mt)
#pragma unroll
        for (int nt = 0; nt < NT; ++nt)
          acc[mt][nt] = __builtin_amdgcn_mfma_f32_16x16x32_bf16(al[mt], bh[nt], acc[mt][nt], 0, 0, 0);
      __builtin_amdgcn_s_setprio(0);
      __builtin_amdgcn_sched_barrier(0);
    } else {
      // ---- stage-1 shape (MT=4, NT=2): 3 bar-windows x 8 MFMA ----
      bf16x8 ah[4], al[4], bh[2], bl[2];
      // ph0: Ah + Bh; issue Ah,Al DMAs
#pragma unroll
      for (int mt = 0; mt < 4; ++mt) ah[mt] = LDAh(buf, wm * MT + mt);
#pragma unroll
      for (int nt = 0; nt < 2; ++nt) bh[nt] = LDBh(buf, wn * NT + nt);
      if (st) { stageAh(nbuf, ts); stageAl(nbuf, ts); }
      barrier_fenced();
      asm volatile("s_waitcnt lgkmcnt(0)" ::: "memory");
      __builtin_amdgcn_sched_barrier(0);
      __builtin_amdgcn_s_setprio(1);
#pragma unroll
      for (int mt = 0; mt < 4; ++mt)
#pragma unroll
        for (int nt = 0; nt < 2; ++nt)
          acc[mt][nt] = __builtin_amdgcn_mfma_f32_16x16x32_bf16(ah[mt], bh[nt], acc[mt][nt], 0, 0, 0);
      __builtin_amdgcn_s_setprio(0);
      __builtin_amdgcn_sched_barrier(0);
      // ph1: Bl; issue Bh,Bl DMAs
      barrier_fenced();
#pragma unroll
      for (int nt = 0; nt < 2; ++nt) bl[nt] = LDBl(buf, wn * NT + nt);
      if (st) { stageBh(nbuf, ts); stageBl(nbuf, ts); }
      barrier_fenced();
      asm volatile("s_waitcnt lgkmcnt(0)" ::: "memory");
      __builtin_amdgcn_sched_barrier(0);
      __builtin_amdgcn_s_setprio(1);
#pragma unroll
      for (int mt = 0; mt < 4; ++mt)
#pragma unroll
        for (int nt = 0; nt < 2; ++nt)
          acc[mt][nt] = __builtin_amdgcn_mfma_f32_16x16x32_bf16(ah[mt], bl[nt], acc[mt][nt], 0, 0, 0);
      __builtin_amdgcn_s_setprio(0);
      __builtin_amdgcn_sched_barrier(0);
      // ph2: Al
      barrier_fenced();
#pragma unroll
      for (int mt = 0; mt < 4; ++mt) al[mt] = LDAl(buf, wm * MT + mt);
      barrier_fenced();
      asm volatile("s_waitcnt lgkmcnt(0)" ::: "memory");
      __builtin_amdgcn_sched_barrier(0);
      __builtin_amdgcn_s_setprio(1);
#pragma unroll
      for (int mt = 0; mt < 4; ++mt)
#pragma unroll
        for (int nt = 0; nt < 2; ++nt)
          acc[mt][nt] = __builtin_amdgcn_mfma_f32_16x16x32_bf16(al[mt], bh[nt], acc[mt][nt], 0, 0, 0);
      __builtin_amdgcn_s_setprio(0);
      __builtin_amdgcn_sched_barrier(0);
    }

    // ---- boundary ----
    __builtin_amdgcn_sched_barrier(0);
    if constexpr (DEPTH == 1) {
      asm volatile("s_waitcnt vmcnt(0)" ::: "memory");
    } else {
      if (t < NTILES - 3)
        asm volatile("s_waitcnt vmcnt(%0)" :: "n"(2 * DM) : "memory");
      else if (t == NTILES - 3)
        asm volatile("s_waitcnt vmcnt(%0)" :: "n"(DM) : "memory");
      else
        asm volatile("s_waitcnt vmcnt(0)" ::: "memory");
    }
    barrier_fenced();
  }

  // Epilogue. C/D layout (m89/m91): col(n) = lane&15, row(m) = (lane>>4)*4 + reg.
  const int cm0 = bm + wm * (BM / WM);
  const int cn0 = bn + wn * (BN / WN);
#pragma unroll
  for (int mt = 0; mt < MT; ++mt) {
#pragma unroll
    for (int nt = 0; nt < NT; ++nt) {
      const int col = cn0 + nt * 16 + lr;
      const int row0 = cm0 + mt * 16 + ls * 4;
      if constexpr (EPI == 0) {
#pragma unroll
        for (int r = 0; r < 4; ++r)
          C[(size_t)(row0 + r) * N + col] = acc[mt][nt][r];
      } else {
#pragma unroll
        for (int r = 0; r < 4; ++r) {
          const float p = acc[mt][nt][r];
          const unsigned short h = f2bf(p);
          const unsigned short l = f2bf(p - bf2f(h));
          const size_t base = (size_t)(row0 + r) * 1024 + col;
          Ph[base] = h;
          Pl[base] = l;
        }
      }
    }
  }
}

// In-place row softmax, N=4096, one block per row, 16 floats/thread in regs.
__global__ __launch_bounds__(256)
void softmax_inplace(float* __restrict__ C, int N) {
  float4* r4 = (float4*)(C + (size_t)blockIdx.x * N);
  const int t = threadIdx.x;
  float4 v[4];
  float mx = -3.0e38f;
#pragma unroll
  for (int i = 0; i < 4; ++i) {
    v[i] = r4[t + i * 256];
    mx = fmaxf(mx, fmaxf(fmaxf(v[i].x, v[i].y), fmaxf(v[i].z, v[i].w)));
  }
#pragma unroll
  for (int o = 32; o; o >>= 1) mx = fmaxf(mx, __shfl_xor(mx, o, 64));
  __shared__ float smax[4], ssum[4];
  const int w = t >> 6;
  if ((t & 63) == 0) smax[w] = mx;
  __syncthreads();
  mx = fmaxf(fmaxf(smax[0], smax[1]), fmaxf(smax[2], smax[3]));
  float s = 0.f;
#pragma unroll
  for (int i = 0; i < 4; ++i) {
    v[i].x = __expf(v[i].x - mx);
    v[i].y = __expf(v[i].y - mx);
    v[i].z = __expf(v[i].z - mx);
    v[i].w = __expf(v[i].w - mx);
    s += (v[i].x + v[i].y) + (v[i].z + v[i].w);
  }
#pragma unroll
  for (int o = 32; o; o >>= 1) s += __shfl_xor(s, o, 64);
  if ((t & 63) == 0) ssum[w] = s;
  __syncthreads();
  const float inv = 1.0f / (ssum[0] + ssum[1] + ssum[2] + ssum[3]);
#pragma unroll
  for (int i = 0; i < 4; ++i) {
    v[i].x *= inv; v[i].y *= inv; v[i].z *= inv; v[i].w *= inv;
    r4[t + i * 256] = v[i];
  }
}

extern "C" void kernel_launch(void* const* d_in, const int* in_sizes, int n_in,
                              void* d_out, int out_size, void* d_ws, size_t ws_size,
                              hipStream_t stream) {
  const float* out_state = (const float*)d_in[0];  // [4096,1024]
  const float* history   = (const float*)d_in[1];  // [4096,1024]
  const float* W         = (const float*)d_in[2];  // [1024,1024]
  float* out = (float*)d_out;                      // [4096,4096]

  unsigned short* Hh = (unsigned short*)d_ws;                 // 4096x1024 each
  unsigned short* Hl = Hh + (size_t)4096 * 1024;
  unsigned short* Wh = Hl + (size_t)4096 * 1024;              // 1024x1024
  unsigned short* Wl = Wh + (size_t)1024 * 1024;
  unsigned short* Ah = Wl + (size_t)1024 * 1024;              // 4096x1024
  unsigned short* Al = Ah + (size_t)4096 * 1024;
  unsigned short* Ph = Al + (size_t)4096 * 1024;              // 4096x1024
  unsigned short* Pl = Ph + (size_t)4096 * 1024;

  split_kernel<<<4096, 256, 0, stream>>>(history, Hh, Hl);
  split_kernel<<<1024, 256, 0, stream>>>(W, Wh, Wl);
  split_kernel<<<4096, 256, 0, stream>>>(out_state, Ah, Al);

  // proj -> Ph,Pl. 128x128, 8 waves, 4 bufs x 32 KB, depth-3 counted vmcnt,
  // 3 bar-windows x 8 MFMA per 32-k slab, 32 slabs. Grid 32x8 = 256.
  gemm4<128, 128, 2, 4, 4, 3, 1, 32, 8, 4><<<256, 512, 0, stream>>>(
      Hh, Hl, Wh, Wl, nullptr, Ph, Pl, 4096, 1024);

  // energies -> d_out. 256x256, 8 waves, 2 bufs x 64 KB, depth-1 (boundary
  // drain is staging-rate-limited anyway), 5 bar-windows per slab, 32 slabs.
  // Staged bytes 2 MB/block (was 3): the actual lever. Grid 16x16 = 256.
  gemm4<256, 256, 2, 4, 2, 1, 0, 16, 4, 8><<<256, 512, 0, stream>>>(
      Ah, Al, Ph, Pl, out, nullptr, nullptr, 4096, 4096);

  softmax_inplace<<<4096, 256, 0, stream>>>(out, 4096);
}